// Round 14
// baseline (53.583 us; speedup 1.0000x reference)
//
#include <hip/hip_runtime.h>
#include <math.h>

#define NEGV  (-1e30f)
#define LOG2E 1.44269504088896340736f
#define LN2   0.69314718055994530942f

typedef __attribute__((ext_vector_type(8))) _Float16 half8;
typedef __attribute__((ext_vector_type(2))) __fp16   fp16x2;  // cvt_pkrtz return type
typedef __attribute__((ext_vector_type(4))) float f32x4;

// Single-instruction base-2 transcendentals (v_exp_f32 / v_log_f32).
__device__ __forceinline__ float exp2_fast(float a) { return __builtin_amdgcn_exp2f(a); }
__device__ __forceinline__ float log2_fast(float a) { return __builtin_amdgcn_logf(a); }

// 8 fp32 -> 8 fp16 via v_cvt_pkrtz (4 VALU ops).
__device__ __forceinline__ half8 cvt8(float4 a, float4 b) {
    union { half8 v; fp16x2 p[4]; } u;
    u.p[0] = __builtin_amdgcn_cvt_pkrtz(a.x, a.y);
    u.p[1] = __builtin_amdgcn_cvt_pkrtz(a.z, a.w);
    u.p[2] = __builtin_amdgcn_cvt_pkrtz(b.x, b.y);
    u.p[3] = __builtin_amdgcn_cvt_pkrtz(b.z, b.w);
    return u.v;
}

// ws layout (floats): [0..63] wg_full[g] = (mw[g]-logZ)*LOG2E
//                     [64..] theta fp16 frags: slot s = gt*2+kt (8 slots),
//                            addr = 64 + (s*64 + lane)*4   (half8 = 4 floats)
#define WS_FLOATS_NEEDED (64 + 8 * 64 * 4)

__global__ void prep_kernel(const float* __restrict__ theta,
                            const float* __restrict__ mw,
                            float* __restrict__ ws)
{
    const int lane = threadIdx.x;  // 64 threads, 1 wave
    const int c15  = lane & 15;
    const int q    = lane >> 4;

    const float v = mw[lane];
    float m = v;
#pragma unroll
    for (int s = 32; s >= 1; s >>= 1) m = fmaxf(m, __shfl_xor(m, s, 64));
    float e = __expf(v - m);
#pragma unroll
    for (int s = 32; s >= 1; s >>= 1) e += __shfl_xor(e, s, 64);
    const float logZ = m + __logf(e);
    ws[lane] = (v - logZ) * LOG2E;

#pragma unroll
    for (int gt = 0; gt < 4; ++gt) {
        const float* tr = theta + (size_t)((gt << 4) + c15) * 64 + (q << 3);
#pragma unroll
        for (int kt = 0; kt < 2; ++kt) {
            float4 a = *(const float4*)(tr + kt * 32);
            float4 c = *(const float4*)(tr + kt * 32 + 4);
            a.x *= LOG2E; a.y *= LOG2E; a.z *= LOG2E; a.w *= LOG2E;
            c.x *= LOG2E; c.y *= LOG2E; c.z *= LOG2E; c.w *= LOG2E;
            const half8 h = cvt8(a, c);
            const int s = (gt << 1) + kt;
            *(half8*)&ws[64 + ((size_t)(s * 64 + lane)) * 4] = h;
        }
    }
}

// ONE WAVE PER BATCH (64-thread blocks). The wave owns all 64 g x 128 l:
//  - B-fragments read from LDS exactly ONCE (16 b128), reused across all 4
//    g-tiles in registers -> no 4x cross-wave read redundancy (R10's cost).
//  - ZERO barriers: stage->read ordering is wave-internal (lgkmcnt).
//  - softmax fully wave-local: phase 1 = in-lane(8 nt) + shfl{1,2,4,8} per
//    g-reg; phase 2 = in-lane 16-term dot with e4 + shfl{16,32} -> direct
//    global store. No red_s round-trip, no epilogue phase.
// acc = 128 VGPRs/lane (4gt x 8nt x f32x4) -> ~2 waves/SIMD occupancy; the
// bet: zero redundancy + zero sync beats occupancy (R8 showed occupancy was
// not binding). Log2-domain, no max subtraction (bounded utilities; masked
// slots contribute exactly 0).
template<bool USE_WS>
__global__ __launch_bounds__(64, 2) void mixed_logit_kernel(
    const float* __restrict__ x,      // [B,128,64]
    const int*   __restrict__ lens,   // [B]
    const float* __restrict__ theta,  // [64,64]
    const float* __restrict__ mw,     // [64]
    const float* __restrict__ ws,     // prep output (if USE_WS)
    float* __restrict__ out)          // [B,128]
{
    __shared__ __align__(16) unsigned char xbuf[128 * 144];  // 18432 B

    const int lane = threadIdx.x;
    const int c15  = lane & 15;
    const int q    = lane >> 4;
    const int b    = blockIdx.x;
    const int len  = lens[b];

    // ---- stage x: 16 pair-loads (32 B/lane, coalesced) -> fp16 LDS rows ----
    // row stride 144 B (9x16B odd -> conflict-free-floor b128 W/R).
    {
        const float4* xp = (const float4*)(x + (size_t)b * 8192);
#pragma unroll
        for (int k = 0; k < 16; ++k) {
            const int j2 = (k << 6) + lane;     // pair idx: row=j2>>3, p8=j2&7
            const float4 a = xp[j2 * 2];
            const float4 c = xp[j2 * 2 + 1];
            const half8 h = cvt8(a, c);
            *(half8*)(xbuf + (j2 >> 3) * 144 + (j2 & 7) * 16) = h;
        }
    }

    // ---- theta fragments (all 8 slots) + mixture constants ----
    half8 th[4][2];
    float wg[4][4];   // [gt][i] for g = gt*16 + q*4 + i
    if constexpr (USE_WS) {
#pragma unroll
        for (int gt = 0; gt < 4; ++gt)
#pragma unroll
            for (int kt = 0; kt < 2; ++kt)
                th[gt][kt] = *(const half8*)&ws[64 + ((size_t)((((gt << 1) + kt) * 64) + lane)) * 4];
#pragma unroll
        for (int gt = 0; gt < 4; ++gt) {
            const f32x4 wv = *(const f32x4*)&ws[(gt << 4) + (q << 2)];
#pragma unroll
            for (int i = 0; i < 4; ++i) wg[gt][i] = wv[i];
        }
    } else {
#pragma unroll
        for (int gt = 0; gt < 4; ++gt) {
            const float* tr = theta + (size_t)((gt << 4) + c15) * 64 + (q << 3);
#pragma unroll
            for (int kt = 0; kt < 2; ++kt) {
                float4 a = *(const float4*)(tr + kt * 32);
                float4 c = *(const float4*)(tr + kt * 32 + 4);
                a.x *= LOG2E; a.y *= LOG2E; a.z *= LOG2E; a.w *= LOG2E;
                c.x *= LOG2E; c.y *= LOG2E; c.z *= LOG2E; c.w *= LOG2E;
                th[gt][kt] = cvt8(a, c);
            }
        }
        const float mwl = mw[lane];
        float mmax = mwl;
#pragma unroll
        for (int s = 32; s >= 1; s >>= 1) mmax = fmaxf(mmax, __shfl_xor(mmax, s, 64));
        float me = __expf(mwl - mmax);
#pragma unroll
        for (int s = 32; s >= 1; s >>= 1) me += __shfl_xor(me, s, 64);
        const float logZ = mmax + __logf(me);
#pragma unroll
        for (int gt = 0; gt < 4; ++gt)
#pragma unroll
            for (int i = 0; i < 4; ++i)
                wg[gt][i] = (mw[(gt << 4) + (q << 2) + i] - logZ) * LOG2E;
    }

    // ---- GEMM: 8 nt x 2 kt frag reads (ONCE), reused across 4 gt ----
    f32x4 acc[4][8];
#pragma unroll
    for (int gt = 0; gt < 4; ++gt)
#pragma unroll
        for (int nt = 0; nt < 8; ++nt) acc[gt][nt] = (f32x4){0.f, 0.f, 0.f, 0.f};

#pragma unroll
    for (int nt = 0; nt < 8; ++nt) {
        const unsigned char* rb = xbuf + ((nt << 4) + c15) * 144 + (q << 4);
        const half8 x0 = *(const half8*)(rb);
        const half8 x1 = *(const half8*)(rb + 64);
#pragma unroll
        for (int gt = 0; gt < 4; ++gt) {
            acc[gt][nt] = __builtin_amdgcn_mfma_f32_16x16x32_f16(th[gt][0], x0, acc[gt][nt], 0, 0, 0);
            acc[gt][nt] = __builtin_amdgcn_mfma_f32_16x16x32_f16(th[gt][1], x1, acc[gt][nt], 0, 0, 0);
        }
    }

    // ---- p = exp2(util); masked l contribute exactly 0 ----
    bool vm[8];
#pragma unroll
    for (int nt = 0; nt < 8; ++nt) vm[nt] = ((nt << 4) + c15) < len;

#pragma unroll
    for (int gt = 0; gt < 4; ++gt)
#pragma unroll
        for (int nt = 0; nt < 8; ++nt)
#pragma unroll
            for (int i = 0; i < 4; ++i) {
                const float pv = exp2_fast(acc[gt][nt][i]);
                acc[gt][nt][i] = vm[nt] ? pv : 0.f;
            }

    // ---- phase 1: denom over 128 l per g; e4 = exp2(wg - lse2) ----
    float e4[4][4];
#pragma unroll
    for (int gt = 0; gt < 4; ++gt)
#pragma unroll
        for (int i = 0; i < 4; ++i) {
            float e = 0.f;
#pragma unroll
            for (int nt = 0; nt < 8; ++nt) e += acc[gt][nt][i];
#pragma unroll
            for (int s = 1; s < 16; s <<= 1) e += __shfl_xor(e, s, 64);
            e4[gt][i] = exp2_fast(wg[gt][i] - log2_fast(e));
        }

    // ---- phase 2: s2[nt] = sum over all 64 g of p*e4; direct store ----
#pragma unroll
    for (int nt = 0; nt < 8; ++nt) {
        float s2 = 0.f;
#pragma unroll
        for (int gt = 0; gt < 4; ++gt) {
            s2 = fmaf(acc[gt][nt][0], e4[gt][0], s2);
            s2 = fmaf(acc[gt][nt][1], e4[gt][1], s2);
            s2 = fmaf(acc[gt][nt][2], e4[gt][2], s2);
            s2 = fmaf(acc[gt][nt][3], e4[gt][3], s2);
        }
        s2 += __shfl_xor(s2, 16, 64);
        s2 += __shfl_xor(s2, 32, 64);
        if (q == 0) {
            const int l = (nt << 4) + c15;
            out[(size_t)b * 128 + l] = (l < len) ? LN2 * log2_fast(s2) : NEGV;
        }
    }
}

extern "C" void kernel_launch(void* const* d_in, const int* in_sizes, int n_in,
                              void* d_out, int out_size, void* d_ws, size_t ws_size,
                              hipStream_t stream) {
    const float* x     = (const float*)d_in[0];
    const int*   lens  = (const int*)d_in[1];
    const float* theta = (const float*)d_in[2];
    const float* mw    = (const float*)d_in[3];
    float* out = (float*)d_out;
    const int B = in_sizes[1];  // 8192

    if (ws_size >= (size_t)WS_FLOATS_NEEDED * sizeof(float)) {
        float* ws = (float*)d_ws;
        prep_kernel<<<1, 64, 0, stream>>>(theta, mw, ws);
        mixed_logit_kernel<true><<<B, 64, 0, stream>>>(x, lens, theta, mw, ws, out);
    } else {
        mixed_logit_kernel<false><<<B, 64, 0, stream>>>(x, lens, theta, mw, nullptr, out);
    }
}

// Round 15
// 44.410 us; speedup vs baseline: 1.2066x; 1.2066x over previous
//
#include <hip/hip_runtime.h>
#include <math.h>

#define NEGV  (-1e30f)
#define LOG2E 1.44269504088896340736f
#define LN2   0.69314718055994530942f

typedef __attribute__((ext_vector_type(8))) _Float16 half8;
typedef __attribute__((ext_vector_type(2))) __fp16   fp16x2;  // cvt_pkrtz return type
typedef __attribute__((ext_vector_type(4))) float f32x4;

// Single-instruction base-2 transcendentals (v_exp_f32 / v_log_f32).
__device__ __forceinline__ float exp2_fast(float a) { return __builtin_amdgcn_exp2f(a); }
__device__ __forceinline__ float log2_fast(float a) { return __builtin_amdgcn_logf(a); }

// 8 fp32 -> 8 fp16 via v_cvt_pkrtz (4 VALU ops).
__device__ __forceinline__ half8 cvt8(float4 a, float4 b) {
    union { half8 v; fp16x2 p[4]; } u;
    u.p[0] = __builtin_amdgcn_cvt_pkrtz(a.x, a.y);
    u.p[1] = __builtin_amdgcn_cvt_pkrtz(a.z, a.w);
    u.p[2] = __builtin_amdgcn_cvt_pkrtz(b.x, b.y);
    u.p[3] = __builtin_amdgcn_cvt_pkrtz(b.z, b.w);
    return u.v;
}

// R13 structure (best measured: 49.1 us), minus the serial prep_kernel.
// One block = one batch, 4 waves; wave w owns g in [16w,16w+16), all 128 l.
// x staged once in LDS as fp16 (row stride 144 B = 9x16B odd ->
// conflict-free-floor b128). Single fp16 MFMA per K-tile. Log2-domain
// softmax, no max subtraction (bounded utilities; masked slots -> exp2 == 0
// exactly). exp2-reuse: p = exp2(acc) once; phase 2 = dot(p, e4).
// NEW: theta/mw prep INLINED per wave (each wave needs only its own 2 theta
// slots: 4 float4 L2-hot loads + 8 cvt + one 64-wide mw log-softmax), issued
// in the shadow of the 8 in-flight x loads. Removes the 1-block prep kernel
// that serialized ~3-6 us of launch+exec ahead of the 8192-block main grid.
__global__ __launch_bounds__(256, 6) void mixed_logit_kernel(
    const float* __restrict__ x,      // [B,128,64]
    const int*   __restrict__ lens,   // [B]
    const float* __restrict__ theta,  // [64,64]
    const float* __restrict__ mw,     // [64]
    float* __restrict__ out)          // [B,128]
{
    __shared__ __align__(16) unsigned char xbuf[128 * 144];  // 18432 B
    __shared__ float red_s[4][128];                          // 2 KB

    const int tid  = threadIdx.x;
    const int lane = tid & 63;
    const int w    = tid >> 6;
    const int c15  = lane & 15;
    const int q    = lane >> 4;
    const int b    = blockIdx.x;
    const int len  = lens[b];

    // ---- x loads first: 8 coalesced float4 loads/thread (HBM starts now) ----
    float4 ra[8];
    {
        const float4* xp = (const float4*)(x + (size_t)b * 8192);
#pragma unroll
        for (int i = 0; i < 4; ++i) {
            const int j2 = (i << 8) + tid;
            ra[2 * i]     = xp[j2 * 2];
            ra[2 * i + 1] = xp[j2 * 2 + 1];
        }
    }

    // ---- inline theta/mw prep (overlaps x-load latency; theta is L2-hot) ----
    half8 th[2];
    float wg[4];
    {
        const float* tr = theta + (size_t)((w << 4) + c15) * 64 + (q << 3);
#pragma unroll
        for (int kt = 0; kt < 2; ++kt) {
            float4 a = *(const float4*)(tr + kt * 32);
            float4 c = *(const float4*)(tr + kt * 32 + 4);
            a.x *= LOG2E; a.y *= LOG2E; a.z *= LOG2E; a.w *= LOG2E;
            c.x *= LOG2E; c.y *= LOG2E; c.z *= LOG2E; c.w *= LOG2E;
            th[kt] = cvt8(a, c);
        }
        const float mwl = mw[lane];
        float mmax = mwl;
#pragma unroll
        for (int s = 32; s >= 1; s >>= 1) mmax = fmaxf(mmax, __shfl_xor(mmax, s, 64));
        float me = __expf(mwl - mmax);
#pragma unroll
        for (int s = 32; s >= 1; s >>= 1) me += __shfl_xor(me, s, 64);
        const float logZ = mmax + __logf(me);
#pragma unroll
        for (int i = 0; i < 4; ++i)
            wg[i] = (mw[(w << 4) + (q << 2) + i] - logZ) * LOG2E;
    }

    // ---- cvt + stage into LDS ----
#pragma unroll
    for (int i = 0; i < 4; ++i) {
        const int j2 = (i << 8) + tid;   // row = j2>>3, p8 = j2&7
        const half8 h = cvt8(ra[2 * i], ra[2 * i + 1]);
        *(half8*)(xbuf + (j2 >> 3) * 144 + (j2 & 7) * 16) = h;
    }
    __syncthreads();

    // ---- GEMM: 8 N-tiles x 2 K-tiles, single fp16 MFMA each ----
    f32x4 acc[8];
#pragma unroll
    for (int nt = 0; nt < 8; ++nt) acc[nt] = (f32x4){0.f, 0.f, 0.f, 0.f};

#pragma unroll
    for (int nt = 0; nt < 8; ++nt) {
        const unsigned char* rb = xbuf + ((nt << 4) + c15) * 144 + (q << 4);
        const half8 x0 = *(const half8*)(rb);
        const half8 x1 = *(const half8*)(rb + 64);
        acc[nt] = __builtin_amdgcn_mfma_f32_16x16x32_f16(th[0], x0, acc[nt], 0, 0, 0);
        acc[nt] = __builtin_amdgcn_mfma_f32_16x16x32_f16(th[1], x1, acc[nt], 0, 0, 0);
    }

    // ---- p = exp2(util), masked slots exactly 0 (computed ONCE, reused) ----
#pragma unroll
    for (int nt = 0; nt < 8; ++nt) {
        const bool v = ((nt << 4) + c15) < len;
#pragma unroll
        for (int i = 0; i < 4; ++i) {
            const float pv = exp2_fast(acc[nt][i]);
            acc[nt][i] = v ? pv : 0.f;      // acc now holds p
        }
    }

    // ---- phase 1: denom over l per g (in-lane sum + shfl {1,2,4,8}) ----
    float e4[4];
#pragma unroll
    for (int i = 0; i < 4; ++i) {
        float e = 0.f;
#pragma unroll
        for (int nt = 0; nt < 8; ++nt) e += acc[nt][i];
#pragma unroll
        for (int s = 1; s < 16; s <<= 1) e += __shfl_xor(e, s, 64);
        e4[i] = exp2_fast(wg[i] - log2_fast(e));   // per-g scale factor
    }

    // ---- phase 2: s2[nt] = sum_i p[nt][i] * e4[i]; cross-q via shfl ----
#pragma unroll
    for (int nt = 0; nt < 8; ++nt) {
        float s2 = acc[nt][0] * e4[0];
        s2 = fmaf(acc[nt][1], e4[1], s2);
        s2 = fmaf(acc[nt][2], e4[2], s2);
        s2 = fmaf(acc[nt][3], e4[3], s2);
        s2 += __shfl_xor(s2, 16, 64);
        s2 += __shfl_xor(s2, 32, 64);
        if ((nt >> 1) == q) {           // static reg index, predicated write
            red_s[w][(nt << 4) + c15] = s2;
        }
    }
    __syncthreads();

    // ---- final: sum 4 wave-partials per l; log2 -> ln; finite sentinel ----
    if (tid < 128) {
        const int l = tid;
        const float S = red_s[0][l] + red_s[1][l] + red_s[2][l] + red_s[3][l];
        const float o = LN2 * log2_fast(S);
        out[(size_t)b * 128 + l] = (l < len) ? o : NEGV;
    }
}

extern "C" void kernel_launch(void* const* d_in, const int* in_sizes, int n_in,
                              void* d_out, int out_size, void* d_ws, size_t ws_size,
                              hipStream_t stream) {
    const float* x     = (const float*)d_in[0];
    const int*   lens  = (const int*)d_in[1];
    const float* theta = (const float*)d_in[2];
    const float* mw    = (const float*)d_in[3];
    float* out = (float*)d_out;
    const int B = in_sizes[1];  // 8192
    mixed_logit_kernel<<<B, 256, 0, stream>>>(x, lens, theta, mw, out);
}